// Round 1
// 262.142 us; speedup vs baseline: 1.0004x; 1.0004x over previous
//
#include <hip/hip_runtime.h>

// Problem constants
#define NB 64
#define NU 9
#define NV 9
#define UV 81
#define HWSZ 9216          // 96*96
#define TPX 64             // pixels per block = 1 wave

typedef float f32x4 __attribute__((ext_vector_type(4)));
typedef const float __attribute__((address_space(1)))* gptr_t;
typedef float       __attribute__((address_space(3)))* sptr_t;

// One wave per block, 64-pixel tile.
// LDS = 80 rows * 64 px * 4 B = 20480 B EXACTLY -> 160 KiB / 20480 = 8 blocks/CU
// (was 21504 B -> 7 blocks/CU). Row 80 bypasses LDS: one per-lane dword load
// (256 B coalesced wave load, 1/81 of traffic).
// Staging rows 0..79 uses __builtin_amdgcn_global_load_lds width=16: the LDS
// dest is wave-uniform base + lane*16, which IS our layout -- iteration k,
// lane l writes floats k*256 + 4l == plane (4k + (l>>4)), px (l&15)*4, i.e.
// lds[p*64 + px]. No VGPR round-trip, no ds_write, ~60 fewer staging VGPRs.
// LDS reads lds[i*64+lane] are lane-consecutive (2-way conflict = free, m136).
__global__ __launch_bounds__(64) void vcn_kernel(const float* __restrict__ x,
                                                 float* __restrict__ out) {
    __shared__ __align__(16) float lds[80 * TPX];   // 20480 B

    const int lane = threadIdx.x;      // 0..63
    const int blk  = blockIdx.x;
    const int b    = blk / 144;        // 9216 / 64 = 144 tiles per batch
    const int hw0  = (blk - b * 144) * TPX;

    const float* xb = x + (size_t)b * UV * HWSZ + hw0;

    // ---- Async-stage 80 plane rows into LDS: 20 x global_load_lds(16B) ----
    const int pj = lane >> 4;          // which of 4 planes this lane serves
    const int px = (lane & 15) * 4;    // pixel offset within the 64-px row
#pragma unroll
    for (int k = 0; k < 20; ++k) {
        const int p = 4 * k + pj;      // 0..79, no tail clamp needed
        __builtin_amdgcn_global_load_lds((gptr_t)(xb + (size_t)p * HWSZ + px),
                                         (sptr_t)(lds + k * 4 * TPX),
                                         16, 0, 0);
    }
    // Row 80 straight to register (coalesced 256 B wave load).
    float v80 = xb[(size_t)80 * HWSZ + lane];

    __syncthreads();                   // single wave: drains counters + barrier
    asm volatile("s_waitcnt vmcnt(0)" ::: "memory");  // belt-and-braces: LDS
                                       // writes from global_load_lds count in
                                       // vmcnt, not lgkmcnt

    // ---- This pixel's 81-value column into registers ----
    float v[UV];
#pragma unroll
    for (int i = 0; i < 80; ++i) v[i] = lds[i * TPX + lane];
    v[80] = v80;

    // ---- Argmax (first occurrence on ties, matching jnp.argmax) ----
    float m = v[0];
    int idx = 0;
#pragma unroll
    for (int i = 1; i < UV; ++i) {
        if (v[i] > m) { m = v[i]; idx = i; }
    }
    int uc = idx / NV;
    int vc = idx - uc * NV;

    // ---- Single pass: global + windowed sums ----
    float seg = 0.f, sxg = 0.f, sel = 0.f, sxl = 0.f, sfx = 0.f, sfy = 0.f;
#pragma unroll
    for (int u = 0; u < NU; ++u) {
        bool ur = (u >= uc - 3) & (u <= uc + 3);
        float fu = (float)(u - 4);
#pragma unroll
        for (int w = 0; w < NV; ++w) {
            float t = v[u * NV + w] - m;
            float e = __expf(t);
            seg += e;
            sxg = fmaf(e, t, sxg);
            bool in = ur & (w >= vc - 3) & (w <= vc + 3);
            float e0 = in ? e : 0.f;
            sel += e0;
            sxl = fmaf(e0, t, sxl);
            sfx = fmaf(e0, fu, sfx);
            sfy = fmaf(e0, (float)(w - 4), sfy);
        }
    }

    const float KLOC = 0.25694895f;    // 1/ln(49)
    const float KGLO = 0.22754075f;    // 1/ln(81)
    float il = 1.f / sel, ig = 1.f / seg;

    float* op = out + (size_t)b * 4 * HWSZ + hw0 + lane;
    op[0 * HWSZ] = sfx * il;
    op[1 * HWSZ] = sfy * il;
    op[2 * HWSZ] = (__logf(sel) - sxl * il) * KLOC;
    op[3 * HWSZ] = (__logf(seg) - sxg * ig) * KGLO;
}

extern "C" void kernel_launch(void* const* d_in, const int* in_sizes, int n_in,
                              void* d_out, int out_size, void* d_ws, size_t ws_size,
                              hipStream_t stream) {
    const float* x = (const float*)d_in[0];
    float* out = (float*)d_out;
    const int grid = NB * (HWSZ / TPX);   // 64 * 144 = 9216 blocks of 1 wave
    vcn_kernel<<<grid, 64, 0, stream>>>(x, out);
}